// Round 9
// baseline (506.563 us; speedup 1.0000x reference)
//
#include <hip/hip_runtime.h>
#include <hip/hip_bf16.h>
#include <stdint.h>

#define TSTEPS 4

typedef __bf16 bf16_t;
typedef __attribute__((ext_vector_type(8))) __bf16 bf16x8;
typedef __attribute__((ext_vector_type(16))) float f32x16;

union frag_u { bf16x8 v; unsigned short u[8]; };

// ---------------------------------------------------------------------------
// Fragment-order global layout ("A-frag"): for a matrix X[rows][k] consumed as
// an MFMA operand (A or B of mfma_f32_32x32x16_bf16), store packets of 1 KB:
//   packet p = blk32 * (K/16) + kblk16
//   within packet: lane*16B, lane = (row&31) + 32*((k>>3)&1), elem j = k&7
// A wave's k-stream for fixed blk32 is CONTIGUOUS memory -> lane-linear
// global_load_dwordx4 straight into MFMA fragment registers. No LDS.
// Lane mapping row=l&31, k=half*8+j is HW-verified (R3..R8 absmax 0.0).
// ---------------------------------------------------------------------------

// ---------------------------------------------------------------------------
// Stage 1: input LIF encoder -> spikes directly in A-frag layout. C=128.
// One thread per (packet, lane); 8 contiguous c's per thread; XLA-exact LIF.
// ---------------------------------------------------------------------------
__global__ void spike_encode_frag(const float* __restrict__ x,
                                  bf16_t* __restrict__ s1)
{
    const int M = 8192, C = 128;
    int gid = blockIdx.x * blockDim.x + threadIdx.x;   // 131072 total
    int lane = gid & 63;
    int packet = gid >> 6;                             // 2048 packets
    int m_blk = packet >> 3;                           // C/16 = 8 kblks
    int k_blk = packet & 7;
    int m = m_blk * 32 + (lane & 31);
    int c = k_blk * 16 + (lane >> 5) * 8;
    const float* px = x + (size_t)m * C + c;
    float4 x0 = *(const float4*)px;
    float4 x1 = *(const float4*)(px + 4);
    float xv[8] = {x0.x, x0.y, x0.z, x0.w, x1.x, x1.y, x1.z, x1.w};
    float v[8];
#pragma unroll
    for (int j = 0; j < 8; ++j) v[j] = 0.0f;
    size_t base = (size_t)packet * 512 + lane * 8;
#pragma unroll
    for (int t = 0; t < TSTEPS; ++t) {
        frag_u f;
#pragma unroll
        for (int j = 0; j < 8; ++j) {
            float vv = __fadd_rn(v[j], __fmul_rn(__fsub_rn(xv[j], v[j]), 0.5f));
            bool sp = (vv >= 1.0f);
            f.u[j] = sp ? 0x3F80 : 0;
            v[j] = sp ? 0.0f : vv;
        }
        *(bf16x8*)(s1 + (size_t)t * M * C + base) = f.v;
    }
}

// ---------------------------------------------------------------------------
// Weight prep, all 3 matrices: W [K][N] fp32 -> hi/lo bf16 2-term split,
// written in B-frag layout (blk32 over n, kblk16 over k).
// ---------------------------------------------------------------------------
__global__ void split_transpose_all(const float* __restrict__ enc_W,
                                    const float* __restrict__ W_cells,
                                    bf16_t* __restrict__ W1h, bf16_t* __restrict__ W1l,
                                    bf16_t* __restrict__ W2h, bf16_t* __restrict__ W2l,
                                    bf16_t* __restrict__ W3h, bf16_t* __restrict__ W3l)
{
    const int N = 1024;
    const float* W;
    bf16_t *hi, *lo;
    int K;
    if (blockIdx.z == 0) {
        if (blockIdx.x >= 4) return;
        W = enc_W; hi = W1h; lo = W1l; K = 128;
    } else if (blockIdx.z == 1) {
        W = W_cells; hi = W2h; lo = W2l; K = 1024;
    } else {
        W = W_cells + (size_t)1024 * 1024; hi = W3h; lo = W3l; K = 1024;
    }
    const int NKB = K >> 4;
    __shared__ float tile[32][33];
    int k0 = blockIdx.x * 32, n0 = blockIdx.y * 32;
    int tx = threadIdx.x & 31, ty = threadIdx.x >> 5;
    for (int kk = ty; kk < 32; kk += 8)
        tile[kk][tx] = W[(size_t)(k0 + kk) * N + n0 + tx];
    __syncthreads();
    for (int nn = ty; nn < 32; nn += 8) {
        float wv = tile[tx][nn];                // = W[k0+tx][n0+nn]
        bf16_t h = (bf16_t)wv;
        bf16_t l = (bf16_t)(wv - (float)h);
        int n = n0 + nn, k = k0 + tx;
        size_t o = ((size_t)(n >> 5) * NKB + (k >> 4)) * 512
                 + (size_t)((n & 31) + ((k >> 3) & 1) * 32) * 8 + (k & 7);
        hi[o] = h;
        lo[o] = l;
    }
}

// ---------------------------------------------------------------------------
// Fused MFMA GEMM + multistep LIF.  R9: LDS-free K-loop (AITER-style).
// A (spikes) and B (split weights) both in fragment-order global layout;
// K-loop = contiguous 16B lane-linear loads -> register double-buffer ->
// mfma_f32_32x32x16_bf16. No LDS, no barriers in the loop.
// Block: 256 thr, 4 waves of 32x32 (2m x 2n) -> 64x64 tile; tau=4
// (acc[4] f32x16 = 64 VGPR; all timesteps share each loaded B fragment).
// XCD swizzle: 2 n-tiles-of-64 per XCD -> B (512 KB) L2-resident.
// Epilogue: LIF t-scan in regs (XLA-exact, same hi->lo k-tree as R8);
// non-LAST output is shuffled C-layout -> A-frag layout through a small
// wave-private LDS tile (per block, not per k-iter).
// ---------------------------------------------------------------------------
template <int K, bool LAST>
__global__ __launch_bounds__(256, 3)
void gemm_lif_mfma(const bf16_t* __restrict__ Afrag,
                   const bf16_t* __restrict__ Bh,
                   const bf16_t* __restrict__ Bl,
                   const float* __restrict__ bias,
                   bf16_t* __restrict__ Sout,
                   float* __restrict__ Out,
                   int M, int N)
{
    constexpr int NKB = K >> 4;                 // 16-k blocks (8 or 64, even)
    __shared__ __align__(16) unsigned short sh[4][32 * 40];  // 10 KB, epilogue

    const int tid = threadIdx.x;
    const int lane = tid & 63;
    const int wid = tid >> 6;
    const int l31 = lane & 31;
    const int half = lane >> 5;

    // XCD swizzle (N=1024 -> 16 n-tiles, 2 per XCD)
    int bid = blockIdx.x;
    int xcd = bid & 7, w = bid >> 3;
    const int n_t = (xcd << 1) | (w & 1);
    const int m_t = w >> 1;
    const int m0 = m_t * 64, n0 = n_t * 64;
    const int wave_m = (wid & 1) * 32;
    const int wave_n = (wid >> 1) * 32;
    const int m_blk = (m0 + wave_m) >> 5;
    const int n_blk = (n0 + wave_n) >> 5;

    const size_t tP = (size_t)M * K;            // elems per timestep plane
    const bf16_t* pA = Afrag + (size_t)m_blk * NKB * 512 + lane * 8;
    const bf16_t* pH = Bh + (size_t)n_blk * NKB * 512 + lane * 8;
    const bf16_t* pL = Bl + (size_t)n_blk * NKB * 512 + lane * 8;

    f32x16 acc[TSTEPS];
#pragma unroll
    for (int t = 0; t < TSTEPS; ++t)
        for (int rr = 0; rr < 16; ++rr) acc[t][rr] = 0.0f;

    bf16x8 a0[TSTEPS], a1[TSTEPS], h0v, h1v, l0v, l1v;
#pragma unroll
    for (int t = 0; t < TSTEPS; ++t)
        a0[t] = *(const bf16x8*)(pA + t * tP);
    h0v = *(const bf16x8*)pH;
    l0v = *(const bf16x8*)pL;

    for (int kb = 0; kb < NKB; kb += 2) {
        const int o1 = (kb + 1) * 512;
#pragma unroll
        for (int t = 0; t < TSTEPS; ++t)
            a1[t] = *(const bf16x8*)(pA + t * tP + o1);
        h1v = *(const bf16x8*)(pH + o1);
        l1v = *(const bf16x8*)(pL + o1);

#pragma unroll
        for (int t = 0; t < TSTEPS; ++t) {
            acc[t] = __builtin_amdgcn_mfma_f32_32x32x16_bf16(
                a0[t], h0v, acc[t], 0, 0, 0);
            acc[t] = __builtin_amdgcn_mfma_f32_32x32x16_bf16(
                a0[t], l0v, acc[t], 0, 0, 0);
        }

        if (kb + 2 < NKB) {
            const int o2 = (kb + 2) * 512;
#pragma unroll
            for (int t = 0; t < TSTEPS; ++t)
                a0[t] = *(const bf16x8*)(pA + t * tP + o2);
            h0v = *(const bf16x8*)(pH + o2);
            l0v = *(const bf16x8*)(pL + o2);
        }

#pragma unroll
        for (int t = 0; t < TSTEPS; ++t) {
            acc[t] = __builtin_amdgcn_mfma_f32_32x32x16_bf16(
                a1[t], h1v, acc[t], 0, 0, 0);
            acc[t] = __builtin_amdgcn_mfma_f32_32x32x16_bf16(
                a1[t], l1v, acc[t], 0, 0, 0);
        }
    }

    // --- LIF epilogue: t-scan in registers (XLA-exact arithmetic) ---
    const float bv = bias[n0 + wave_n + l31];
    f32x16 vmem;
#pragma unroll
    for (int rr = 0; rr < 16; ++rr) vmem[rr] = 0.0f;
    uint64_t bits = 0ull;
    unsigned short* myt = &sh[wid][0];

    for (int t = 0; t < TSTEPS; ++t) {
        unsigned short spk[16];
#pragma unroll
        for (int rr = 0; rr < 16; ++rr) {
            float y = __fadd_rn(acc[t][rr], bv);
            float vv = vmem[rr];
            vv = __fadd_rn(vv, __fmul_rn(__fsub_rn(y, vv), 0.5f));
            bool sp = (vv >= 1.0f);
            vmem[rr] = sp ? 0.0f : vv;
            if (LAST) bits |= sp ? (1ull << (rr * 4 + t)) : 0ull;
            else spk[rr] = sp ? 0x3F80 : 0;
        }
        if (!LAST) {
            // C-layout -> LDS (wave-private 32x40 tile)
#pragma unroll
            for (int rr = 0; rr < 16; ++rr) {
                int m_r = (rr & 3) + 8 * (rr >> 2) + 4 * half;
                myt[m_r * 40 + l31] = spk[rr];
            }
            __syncthreads();
            // LDS -> A-frag layout global stores (next layer's k = this n)
#pragma unroll
            for (int kb2 = 0; kb2 < 2; ++kb2) {
                bf16x8 frag = *(const bf16x8*)&myt[l31 * 40 + kb2 * 16 + half * 8];
                size_t kg = (size_t)((n0 + wave_n) >> 4) + kb2;
                *(bf16x8*)(Sout + (size_t)t * M * N
                           + ((size_t)m_blk * (N >> 4) + kg) * 512 + lane * 8) = frag;
            }
            __syncthreads();
        }
    }

    if (LAST) {
#pragma unroll
        for (int rr = 0; rr < 16; ++rr) {
            int m_r = (rr & 3) + 8 * (rr >> 2) + 4 * half;
            int m = m0 + wave_m + m_r;
            int n = n0 + wave_n + l31;
            int cnt = __popc((unsigned)((bits >> (rr * 4)) & 0xFull));
            Out[(size_t)m * N + n] = 0.25f * (float)cnt;
        }
    }
}

// ---------------------------------------------------------------------------
// out2[b][d] = mean over L of out[b][l][d]. Exact in fp32 (quarter-integers).
// ---------------------------------------------------------------------------
__global__ void mean_over_L_kernel(const float* __restrict__ out,
                                   float* __restrict__ out2,
                                   int B, int L, int D)
{
    int id = blockIdx.x * blockDim.x + threadIdx.x;
    if (id >= B * D) return;
    int b = id / D, d = id - b * D;
    const float* p = out + (size_t)b * L * D + d;
    float s = 0.0f;
    for (int l = 0; l < L; ++l) s += p[(size_t)l * D];
    out2[id] = s * (1.0f / (float)L);
}

// ---------------------------------------------------------------------------
extern "C" void kernel_launch(void* const* d_in, const int* in_sizes, int n_in,
                              void* d_out, int out_size, void* d_ws, size_t ws_size,
                              hipStream_t stream)
{
    const float* inputs  = (const float*)d_in[0];  // [16,512,128]
    const float* enc_W   = (const float*)d_in[1];  // [128,1024]
    const float* enc_b   = (const float*)d_in[2];  // [1024]
    const float* W_cells = (const float*)d_in[3];  // [2,1024,1024]
    const float* b_cells = (const float*)d_in[4];  // [2,1024]

    const int B = 16, L = 512, C = 128, D = 1024;
    const int M = B * L;  // 8192

    // ws layout (all fragment-order): s1 8MB | W1h/l 0.5MB | W2h/l 4MB |
    // W3h/l 4MB | h0 64MB | h1 64MB
    char* ws = (char*)d_ws;
    size_t off = 0;
    bf16_t* s1 = (bf16_t*)(ws + off); off += (size_t)TSTEPS * M * C * 2;
    bf16_t* W1h = (bf16_t*)(ws + off); off += (size_t)C * D * 2;
    bf16_t* W1l = (bf16_t*)(ws + off); off += (size_t)C * D * 2;
    bf16_t* W2h = (bf16_t*)(ws + off); off += (size_t)D * D * 2;
    bf16_t* W2l = (bf16_t*)(ws + off); off += (size_t)D * D * 2;
    bf16_t* W3h = (bf16_t*)(ws + off); off += (size_t)D * D * 2;
    bf16_t* W3l = (bf16_t*)(ws + off); off += (size_t)D * D * 2;
    bf16_t* h0 = (bf16_t*)(ws + off); off += (size_t)TSTEPS * M * D * 2;
    bf16_t* h1 = (bf16_t*)(ws + off);

    float* out  = (float*)d_out;          // [M, D]
    float* out2 = out + (size_t)M * D;    // [B, D]

    split_transpose_all<<<dim3(32, 32, 3), 256, 0, stream>>>(
        enc_W, W_cells, W1h, W1l, W2h, W2l, W3h, W3l);

    spike_encode_frag<<<512, 256, 0, stream>>>(inputs, s1);

    const int nblocks = (M / 64) * (D / 64);   // 2048
    gemm_lif_mfma<128, false><<<nblocks, 256, 0, stream>>>(
        s1, W1h, W1l, enc_b, h0, nullptr, M, D);
    gemm_lif_mfma<1024, false><<<nblocks, 256, 0, stream>>>(
        h0, W2h, W2l, b_cells, h1, nullptr, M, D);
    gemm_lif_mfma<1024, true><<<nblocks, 256, 0, stream>>>(
        h1, W3h, W3l, b_cells + D, nullptr, out, M, D);

    mean_over_L_kernel<<<(B * D + 255) / 256, 256, 0, stream>>>(
        out, out2, B, L, D);
}

// Round 10
// 485.822 us; speedup vs baseline: 1.0427x; 1.0427x over previous
//
#include <hip/hip_runtime.h>
#include <hip/hip_bf16.h>
#include <stdint.h>

#define TSTEPS 4

typedef __bf16 bf16_t;
typedef __attribute__((ext_vector_type(8))) __bf16 bf16x8;
typedef __attribute__((ext_vector_type(16))) float f32x16;

union frag_u { bf16x8 v; unsigned short u[8]; };

// gfx9 s_waitcnt immediates: vmcnt low4 [3:0] hi2 [15:14]; expcnt=7,lgkm=15 off
#define VMCNT12 0xF7C
#define VMCNT6  0xF76
#define VMCNT0  0xF70

// ---------------------------------------------------------------------------
// Fragment-order global layout ("A-frag"): packets of 1 KB:
//   packet p = blk32 * (K/16) + kblk16
//   within: lane*16B, lane = (row&31) + 32*((k>>3)&1), elem j = k&7
// Wave k-stream contiguous -> lane-linear global_load_dwordx4 -> MFMA regs.
// ---------------------------------------------------------------------------

// ---------------------------------------------------------------------------
// Stage 1: input LIF encoder -> spikes directly in A-frag layout. C=128.
// ---------------------------------------------------------------------------
__global__ void spike_encode_frag(const float* __restrict__ x,
                                  bf16_t* __restrict__ s1)
{
    const int M = 8192, C = 128;
    int gid = blockIdx.x * blockDim.x + threadIdx.x;   // 131072 total
    int lane = gid & 63;
    int packet = gid >> 6;                             // 2048 packets
    int m_blk = packet >> 3;
    int k_blk = packet & 7;
    int m = m_blk * 32 + (lane & 31);
    int c = k_blk * 16 + (lane >> 5) * 8;
    const float* px = x + (size_t)m * C + c;
    float4 x0 = *(const float4*)px;
    float4 x1 = *(const float4*)(px + 4);
    float xv[8] = {x0.x, x0.y, x0.z, x0.w, x1.x, x1.y, x1.z, x1.w};
    float v[8];
#pragma unroll
    for (int j = 0; j < 8; ++j) v[j] = 0.0f;
    size_t base = (size_t)packet * 512 + lane * 8;
#pragma unroll
    for (int t = 0; t < TSTEPS; ++t) {
        frag_u f;
#pragma unroll
        for (int j = 0; j < 8; ++j) {
            float vv = __fadd_rn(v[j], __fmul_rn(__fsub_rn(xv[j], v[j]), 0.5f));
            bool sp = (vv >= 1.0f);
            f.u[j] = sp ? 0x3F80 : 0;
            v[j] = sp ? 0.0f : vv;
        }
        *(bf16x8*)(s1 + (size_t)t * M * C + base) = f.v;
    }
}

// ---------------------------------------------------------------------------
// Weight prep: W [K][N] fp32 -> hi/lo bf16 split in B-frag layout.
// ---------------------------------------------------------------------------
__global__ void split_transpose_all(const float* __restrict__ enc_W,
                                    const float* __restrict__ W_cells,
                                    bf16_t* __restrict__ W1h, bf16_t* __restrict__ W1l,
                                    bf16_t* __restrict__ W2h, bf16_t* __restrict__ W2l,
                                    bf16_t* __restrict__ W3h, bf16_t* __restrict__ W3l)
{
    const int N = 1024;
    const float* W;
    bf16_t *hi, *lo;
    int K;
    if (blockIdx.z == 0) {
        if (blockIdx.x >= 4) return;
        W = enc_W; hi = W1h; lo = W1l; K = 128;
    } else if (blockIdx.z == 1) {
        W = W_cells; hi = W2h; lo = W2l; K = 1024;
    } else {
        W = W_cells + (size_t)1024 * 1024; hi = W3h; lo = W3l; K = 1024;
    }
    const int NKB = K >> 4;
    __shared__ float tile[32][33];
    int k0 = blockIdx.x * 32, n0 = blockIdx.y * 32;
    int tx = threadIdx.x & 31, ty = threadIdx.x >> 5;
    for (int kk = ty; kk < 32; kk += 8)
        tile[kk][tx] = W[(size_t)(k0 + kk) * N + n0 + tx];
    __syncthreads();
    for (int nn = ty; nn < 32; nn += 8) {
        float wv = tile[tx][nn];
        bf16_t h = (bf16_t)wv;
        bf16_t l = (bf16_t)(wv - (float)h);
        int n = n0 + nn, k = k0 + tx;
        size_t o = ((size_t)(n >> 5) * NKB + (k >> 4)) * 512
                 + (size_t)((n & 31) + ((k >> 3) & 1) * 32) * 8 + (k & 7);
        hi[o] = h;
        lo[o] = l;
    }
}

// ---------------------------------------------------------------------------
// Fused MFMA GEMM + multistep LIF.  R10 = R9 + ring-3 prefetch + MFMA reorder.
// LDS-free K-loop; A/B in frag-order global layout. Block: 256 thr, 4 waves
// of 32x32 (2m x 2n) -> 64x64 tile; tau=4 (acc[4] f32x16, AGPR).
// K-loop per kb (16 k): issue 6 loads for kb+2 (ring slot (s+2)%3) ->
// s_waitcnt vmcnt(12) [only kb's batch must land; 2 newer in flight] ->
// 8 MFMAs ordered hi(t0..t3), lo(t0..t3): dependent-acc distance = 4 instrs.
// Load->use distance = 2 kb-iters (~600+ cyc) covers L2/HBM latency.
// Per-acc hi/lo k-order unchanged from R9 -> bitwise-identical output.
// ---------------------------------------------------------------------------
template <int K, bool LAST>
__global__ __launch_bounds__(256, 2)
void gemm_lif_mfma(const bf16_t* __restrict__ Afrag,
                   const bf16_t* __restrict__ Bh,
                   const bf16_t* __restrict__ Bl,
                   const float* __restrict__ bias,
                   bf16_t* __restrict__ Sout,
                   float* __restrict__ Out,
                   int M, int N)
{
    constexpr int NKB = K >> 4;                 // 8 or 64
    __shared__ __align__(16) unsigned short sh[4][32 * 40];  // 10 KB, epilogue

    const int tid = threadIdx.x;
    const int lane = tid & 63;
    const int wid = tid >> 6;
    const int l31 = lane & 31;
    const int half = lane >> 5;

    // XCD swizzle (N=1024 -> 16 n-tiles, 2 per XCD)
    int bid = blockIdx.x;
    int xcd = bid & 7, w = bid >> 3;
    const int n_t = (xcd << 1) | (w & 1);
    const int m_t = w >> 1;
    const int m0 = m_t * 64, n0 = n_t * 64;
    const int wave_m = (wid & 1) * 32;
    const int wave_n = (wid >> 1) * 32;
    const int m_blk = (m0 + wave_m) >> 5;
    const int n_blk = (n0 + wave_n) >> 5;

    const size_t tP = (size_t)M * K;            // elems per timestep plane
    const bf16_t* pA0 = Afrag + (size_t)m_blk * NKB * 512 + lane * 8;
    const bf16_t* pA1 = pA0 + tP;
    const bf16_t* pA2 = pA0 + 2 * tP;
    const bf16_t* pA3 = pA0 + 3 * tP;
    const bf16_t* pH = Bh + (size_t)n_blk * NKB * 512 + lane * 8;
    const bf16_t* pL = Bl + (size_t)n_blk * NKB * 512 + lane * 8;

    f32x16 acc[TSTEPS];
#pragma unroll
    for (int t = 0; t < TSTEPS; ++t)
        for (int rr = 0; rr < 16; ++rr) acc[t][rr] = 0.0f;

    bf16x8 fa[3][4], fh[3], fl[3];

#define LOADB(kb_, s_) {                                                     \
        const int _o = (kb_) * 512;                                          \
        fa[s_][0] = *(const bf16x8*)(pA0 + _o);                              \
        fa[s_][1] = *(const bf16x8*)(pA1 + _o);                              \
        fa[s_][2] = *(const bf16x8*)(pA2 + _o);                              \
        fa[s_][3] = *(const bf16x8*)(pA3 + _o);                              \
        fh[s_] = *(const bf16x8*)(pH + _o);                                  \
        fl[s_] = *(const bf16x8*)(pL + _o);                                  \
    }

#define MFMASTEP(s_) {                                                       \
        acc[0] = __builtin_amdgcn_mfma_f32_32x32x16_bf16(fa[s_][0], fh[s_], acc[0], 0, 0, 0); \
        acc[1] = __builtin_amdgcn_mfma_f32_32x32x16_bf16(fa[s_][1], fh[s_], acc[1], 0, 0, 0); \
        acc[2] = __builtin_amdgcn_mfma_f32_32x32x16_bf16(fa[s_][2], fh[s_], acc[2], 0, 0, 0); \
        acc[3] = __builtin_amdgcn_mfma_f32_32x32x16_bf16(fa[s_][3], fh[s_], acc[3], 0, 0, 0); \
        acc[0] = __builtin_amdgcn_mfma_f32_32x32x16_bf16(fa[s_][0], fl[s_], acc[0], 0, 0, 0); \
        acc[1] = __builtin_amdgcn_mfma_f32_32x32x16_bf16(fa[s_][1], fl[s_], acc[1], 0, 0, 0); \
        acc[2] = __builtin_amdgcn_mfma_f32_32x32x16_bf16(fa[s_][2], fl[s_], acc[2], 0, 0, 0); \
        acc[3] = __builtin_amdgcn_mfma_f32_32x32x16_bf16(fa[s_][3], fl[s_], acc[3], 0, 0, 0); \
    }

#define STEP(kb_, s_, s2_) {                                                 \
        if ((kb_) + 2 < NKB) {                                               \
            LOADB((kb_) + 2, s2_);                                           \
            __builtin_amdgcn_s_waitcnt(VMCNT12);                             \
        } else if ((kb_) + 1 < NKB) {                                        \
            __builtin_amdgcn_s_waitcnt(VMCNT6);                              \
        } else {                                                             \
            __builtin_amdgcn_s_waitcnt(VMCNT0);                              \
        }                                                                    \
        asm volatile("" ::: "memory");                                       \
        MFMASTEP(s_);                                                        \
    }

    LOADB(0, 0);
    LOADB(1, 1);

    constexpr int REM = NKB % 3;
    for (int kb = 0; kb + 3 <= NKB - REM; kb += 3) {
        STEP(kb + 0, 0, 2);
        STEP(kb + 1, 1, 0);
        STEP(kb + 2, 2, 1);
    }
    if (REM >= 1) STEP(NKB - REM + 0, 0, 2);
    if (REM == 2) STEP(NKB - REM + 1, 1, 0);

#undef STEP
#undef MFMASTEP
#undef LOADB

    // --- LIF epilogue: t-scan in registers (XLA-exact arithmetic) ---
    const float bv = bias[n0 + wave_n + l31];
    f32x16 vmem;
#pragma unroll
    for (int rr = 0; rr < 16; ++rr) vmem[rr] = 0.0f;
    uint64_t bits = 0ull;
    unsigned short* myt = &sh[wid][0];

    for (int t = 0; t < TSTEPS; ++t) {
        unsigned short spk[16];
#pragma unroll
        for (int rr = 0; rr < 16; ++rr) {
            float y = __fadd_rn(acc[t][rr], bv);
            float vv = vmem[rr];
            vv = __fadd_rn(vv, __fmul_rn(__fsub_rn(y, vv), 0.5f));
            bool sp = (vv >= 1.0f);
            vmem[rr] = sp ? 0.0f : vv;
            if (LAST) bits |= sp ? (1ull << (rr * 4 + t)) : 0ull;
            else spk[rr] = sp ? 0x3F80 : 0;
        }
        if (!LAST) {
#pragma unroll
            for (int rr = 0; rr < 16; ++rr) {
                int m_r = (rr & 3) + 8 * (rr >> 2) + 4 * half;
                myt[m_r * 40 + l31] = spk[rr];
            }
            __syncthreads();
#pragma unroll
            for (int kb2 = 0; kb2 < 2; ++kb2) {
                bf16x8 frag = *(const bf16x8*)&myt[l31 * 40 + kb2 * 16 + half * 8];
                size_t kg = (size_t)((n0 + wave_n) >> 4) + kb2;
                *(bf16x8*)(Sout + (size_t)t * M * N
                           + ((size_t)m_blk * (N >> 4) + kg) * 512 + lane * 8) = frag;
            }
            __syncthreads();
        }
    }

    if (LAST) {
#pragma unroll
        for (int rr = 0; rr < 16; ++rr) {
            int m_r = (rr & 3) + 8 * (rr >> 2) + 4 * half;
            int m = m0 + wave_m + m_r;
            int n = n0 + wave_n + l31;
            int cnt = __popc((unsigned)((bits >> (rr * 4)) & 0xFull));
            Out[(size_t)m * N + n] = 0.25f * (float)cnt;
        }
    }
}

// ---------------------------------------------------------------------------
// out2[b][d] = mean over L of out[b][l][d]. Exact in fp32 (quarter-integers).
// ---------------------------------------------------------------------------
__global__ void mean_over_L_kernel(const float* __restrict__ out,
                                   float* __restrict__ out2,
                                   int B, int L, int D)
{
    int id = blockIdx.x * blockDim.x + threadIdx.x;
    if (id >= B * D) return;
    int b = id / D, d = id - b * D;
    const float* p = out + (size_t)b * L * D + d;
    float s = 0.0f;
    for (int l = 0; l < L; ++l) s += p[(size_t)l * D];
    out2[id] = s * (1.0f / (float)L);
}

// ---------------------------------------------------------------------------
extern "C" void kernel_launch(void* const* d_in, const int* in_sizes, int n_in,
                              void* d_out, int out_size, void* d_ws, size_t ws_size,
                              hipStream_t stream)
{
    const float* inputs  = (const float*)d_in[0];  // [16,512,128]
    const float* enc_W   = (const float*)d_in[1];  // [128,1024]
    const float* enc_b   = (const float*)d_in[2];  // [1024]
    const float* W_cells = (const float*)d_in[3];  // [2,1024,1024]
    const float* b_cells = (const float*)d_in[4];  // [2,1024]

    const int B = 16, L = 512, C = 128, D = 1024;
    const int M = B * L;  // 8192

    // ws layout (all fragment-order): s1 8MB | W1h/l 0.5MB | W2h/l 4MB |
    // W3h/l 4MB | h0 64MB | h1 64MB
    char* ws = (char*)d_ws;
    size_t off = 0;
    bf16_t* s1 = (bf16_t*)(ws + off); off += (size_t)TSTEPS * M * C * 2;
    bf16_t* W1h = (bf16_t*)(ws + off); off += (size_t)C * D * 2;
    bf16_t* W1l = (bf16_t*)(ws + off); off += (size_t)C * D * 2;
    bf16_t* W2h = (bf16_t*)(ws + off); off += (size_t)D * D * 2;
    bf16_t* W2l = (bf16_t*)(ws + off); off += (size_t)D * D * 2;
    bf16_t* W3h = (bf16_t*)(ws + off); off += (size_t)D * D * 2;
    bf16_t* W3l = (bf16_t*)(ws + off); off += (size_t)D * D * 2;
    bf16_t* h0 = (bf16_t*)(ws + off); off += (size_t)TSTEPS * M * D * 2;
    bf16_t* h1 = (bf16_t*)(ws + off);

    float* out  = (float*)d_out;          // [M, D]
    float* out2 = out + (size_t)M * D;    // [B, D]

    split_transpose_all<<<dim3(32, 32, 3), 256, 0, stream>>>(
        enc_W, W_cells, W1h, W1l, W2h, W2l, W3h, W3l);

    spike_encode_frag<<<512, 256, 0, stream>>>(inputs, s1);

    const int nblocks = (M / 64) * (D / 64);   // 2048
    gemm_lif_mfma<128, false><<<nblocks, 256, 0, stream>>>(
        s1, W1h, W1l, enc_b, h0, nullptr, M, D);
    gemm_lif_mfma<1024, false><<<nblocks, 256, 0, stream>>>(
        h0, W2h, W2l, b_cells, h1, nullptr, M, D);
    gemm_lif_mfma<1024, true><<<nblocks, 256, 0, stream>>>(
        h1, W3h, W3l, b_cells + D, nullptr, out, M, D);

    mean_over_L_kernel<<<(B * D + 255) / 256, 256, 0, stream>>>(
        out, out2, B, L, D);
}